// Round 8
// baseline (222.950 us; speedup 1.0000x reference)
//
#include <hip/hip_runtime.h>

#define BB    4
#define NN    8192
#define KK    16
#define CIN   64
#define COUTC 64
#define P     16           // fallback monolith M-tile
#define PW    8            // stage-B points per wave

typedef short bf16x8 __attribute__((ext_vector_type(8)));
typedef float f32x4  __attribute__((ext_vector_type(4)));

__device__ __forceinline__ unsigned short f2bf_rne(float f) {
    unsigned int u = __builtin_bit_cast(unsigned int, f);
    u += 0x7fffu + ((u >> 16) & 1u);
    return (unsigned short)(u >> 16);
}

__device__ __forceinline__ unsigned int pack_bf2(float lo, float hi) {
    return (unsigned int)f2bf_rne(lo) | ((unsigned int)f2bf_rne(hi) << 16);
}

// Wt[cout][g], g = half*512 + cin*8 + ml  (logical m = half*8 + ml), 1/16 folded.
__global__ __launch_bounds__(256) void prep_w(const float* __restrict__ W,
                                              unsigned short* __restrict__ Wt) {
    const int o    = blockIdx.x * 256 + threadIdx.x;   // 65536 total
    const int cout = o >> 10;
    const int g    = o & 1023;
    const int pass = g >> 9;
    const int q    = g & 511;
    const int cin  = q >> 3;
    const int m    = pass * 8 + (q & 7);
    Wt[o] = f2bf_rne(W[(cin * 16 + m) * 64 + cout] * (1.0f / 16.0f));
}

// folded layer-1: A1[j] = {a0,a1,a2,b'} per hidden unit j
__global__ void prep_fold(const float* __restrict__ l1w, const float* __restrict__ l1b,
                          const float* __restrict__ centers, float* __restrict__ A1) {
    const int t = threadIdx.x;     // 32 threads
    float bb = l1b[t];
    float a0 = 0.f, a1 = 0.f, a2 = 0.f;
    for (int c = 0; c < 16; ++c) {
        const float w0 = l1w[(c     ) * 32 + t];
        const float w1 = l1w[(16 + c) * 32 + t];
        const float w2 = l1w[(32 + c) * 32 + t];
        a0 += w0; a1 += w1; a2 += w2;
        bb -= centers[c] * w0 + centers[16 + c] * w1 + centers[32 + c] * w2;
    }
    A1[t * 4 + 0] = a0; A1[t * 4 + 1] = a1; A1[t * 4 + 2] = a2; A1[t * 4 + 3] = bb;
}

// ================= stage A: MLP, one thread per (point, k) =================
__global__ __launch_bounds__(256) void mlp_kernel(
    const float* __restrict__ points, const float* __restrict__ next_pts,
    const int*   __restrict__ indices, const float* __restrict__ A1f,
    const float* __restrict__ l2w, const float* __restrict__ l2b,
    const float* __restrict__ l3w, const float* __restrict__ l3b,
    float* __restrict__ h3g)                 // [B*N*K][16] f32
{
    __shared__ float s_A1[32][4];
    __shared__ float s_w2[32][16];
    __shared__ float s_w3[16][16];
    __shared__ float s_b2[16], s_b3[16];
    const int t = threadIdx.x;
    if (t < 128) ((float*)s_A1)[t] = A1f[t];
    for (int i = t; i < 512; i += 256) ((float*)s_w2)[i] = l2w[i];
    if (t < 256) ((float*)s_w3)[t] = l3w[t];
    if (t < 16)  { s_b2[t] = l2b[t]; s_b3[t] = l3b[t]; }
    __syncthreads();

    const int task = blockIdx.x * 256 + t;   // 524288 total
    const int pt   = task >> 4;
    const int b    = pt >> 13;
    const int id   = indices[task];
    const float* pp = points + ((size_t)(b * NN + id)) * 3;
    const float* np = next_pts + (size_t)pt * 3;
    const float px = pp[0] - np[0];
    const float py = pp[1] - np[1];
    const float pz = pp[2] - np[2];

    float h1[32];
    #pragma unroll
    for (int j = 0; j < 32; ++j) {
        const float4 a = *(const float4*)&s_A1[j][0];
        h1[j] = fmaxf(fmaf(px, a.x, fmaf(py, a.y, fmaf(pz, a.z, a.w))), 0.f);
    }
    float h2[16];
    #pragma unroll
    for (int j = 0; j < 16; ++j) h2[j] = s_b2[j];
    #pragma unroll
    for (int i = 0; i < 32; ++i) {
        const float4 q0 = *(const float4*)&s_w2[i][0];
        const float4 q1 = *(const float4*)&s_w2[i][4];
        const float4 q2 = *(const float4*)&s_w2[i][8];
        const float4 q3 = *(const float4*)&s_w2[i][12];
        h2[0]  = fmaf(h1[i], q0.x, h2[0]);  h2[1]  = fmaf(h1[i], q0.y, h2[1]);
        h2[2]  = fmaf(h1[i], q0.z, h2[2]);  h2[3]  = fmaf(h1[i], q0.w, h2[3]);
        h2[4]  = fmaf(h1[i], q1.x, h2[4]);  h2[5]  = fmaf(h1[i], q1.y, h2[5]);
        h2[6]  = fmaf(h1[i], q1.z, h2[6]);  h2[7]  = fmaf(h1[i], q1.w, h2[7]);
        h2[8]  = fmaf(h1[i], q2.x, h2[8]);  h2[9]  = fmaf(h1[i], q2.y, h2[9]);
        h2[10] = fmaf(h1[i], q2.z, h2[10]); h2[11] = fmaf(h1[i], q2.w, h2[11]);
        h2[12] = fmaf(h1[i], q3.x, h2[12]); h2[13] = fmaf(h1[i], q3.y, h2[13]);
        h2[14] = fmaf(h1[i], q3.z, h2[14]); h2[15] = fmaf(h1[i], q3.w, h2[15]);
    }
    #pragma unroll
    for (int j = 0; j < 16; ++j) h2[j] = fmaxf(h2[j], 0.f);
    float h3[16];
    #pragma unroll
    for (int j = 0; j < 16; ++j) h3[j] = s_b3[j];
    #pragma unroll
    for (int i = 0; i < 16; ++i) {
        const float4 q0 = *(const float4*)&s_w3[i][0];
        const float4 q1 = *(const float4*)&s_w3[i][4];
        const float4 q2 = *(const float4*)&s_w3[i][8];
        const float4 q3 = *(const float4*)&s_w3[i][12];
        h3[0]  = fmaf(h2[i], q0.x, h3[0]);  h3[1]  = fmaf(h2[i], q0.y, h3[1]);
        h3[2]  = fmaf(h2[i], q0.z, h3[2]);  h3[3]  = fmaf(h2[i], q0.w, h3[3]);
        h3[4]  = fmaf(h2[i], q1.x, h3[4]);  h3[5]  = fmaf(h2[i], q1.y, h3[5]);
        h3[6]  = fmaf(h2[i], q1.z, h3[6]);  h3[7]  = fmaf(h2[i], q1.w, h3[7]);
        h3[8]  = fmaf(h2[i], q2.x, h3[8]);  h3[9]  = fmaf(h2[i], q2.y, h3[9]);
        h3[10] = fmaf(h2[i], q2.z, h3[10]); h3[11] = fmaf(h2[i], q2.w, h3[11]);
        h3[12] = fmaf(h2[i], q3.x, h3[12]); h3[13] = fmaf(h2[i], q3.y, h3[13]);
        h3[14] = fmaf(h2[i], q3.z, h3[14]); h3[15] = fmaf(h2[i], q3.w, h3[15]);
    }
    float4* o = (float4*)(h3g + (size_t)task * 16);
    o[0] = make_float4(fmaxf(h3[0],0.f),  fmaxf(h3[1],0.f),  fmaxf(h3[2],0.f),  fmaxf(h3[3],0.f));
    o[1] = make_float4(fmaxf(h3[4],0.f),  fmaxf(h3[5],0.f),  fmaxf(h3[6],0.f),  fmaxf(h3[7],0.f));
    o[2] = make_float4(fmaxf(h3[8],0.f),  fmaxf(h3[9],0.f),  fmaxf(h3[10],0.f), fmaxf(h3[11],0.f));
    o[3] = make_float4(fmaxf(h3[12],0.f), fmaxf(h3[13],0.f), fmaxf(h3[14],0.f), fmaxf(h3[15],0.f));
}

// ======== stage B: gather + outer-product + MFMA; 1 wave = 8 points, 2 m-halves ========
__global__ __launch_bounds__(64, 4) void gemm_kernel(
    const float* __restrict__ inp, const int* __restrict__ indices,
    const float* __restrict__ h3g, const unsigned short* __restrict__ Wt,
    const float* __restrict__ bias, float* __restrict__ out)
{
    __shared__ unsigned short s_fb[PW][512];     // 8 KB: [pt][k''-half] bf16, XOR-swizzled
    const int lane = threadIdx.x;                // = cin for phase 2
    const int pt0  = blockIdx.x * PW;
    const int b    = pt0 >> 13;
    const int arow = lane & 15;                  // MFMA A-row / B-col
    const int hi   = lane >> 4;
    const int*   idxp = indices + (size_t)pt0 * KK;
    const float* inb  = inp + (size_t)b * NN * 64;

    const unsigned short* wb0 = Wt + (size_t)( 0 + arow) * 1024 + hi * 8;
    const unsigned short* wb1 = Wt + (size_t)(16 + arow) * 1024 + hi * 8;
    const unsigned short* wb2 = Wt + (size_t)(32 + arow) * 1024 + hi * 8;
    const unsigned short* wb3 = Wt + (size_t)(48 + arow) * 1024 + hi * 8;
    f32x4 acc0 = {0.f,0.f,0.f,0.f}, acc1 = {0.f,0.f,0.f,0.f};
    f32x4 acc2 = {0.f,0.f,0.f,0.f}, acc3 = {0.f,0.f,0.f,0.f};

    #pragma unroll
    for (int h = 0; h < 2; ++h) {                // m-half pass
        // ---- phase 2: f[p2][cin][m-half], lane = cin ----
        #pragma unroll
        for (int p2 = 0; p2 < PW; ++p2) {
            float a0=0.f,a1=0.f,a2=0.f,a3=0.f,a4=0.f,a5=0.f,a6=0.f,a7=0.f;
            const float* hb = h3g + ((size_t)(pt0 + p2) * KK) * 16 + h * 8;
            #pragma unroll
            for (int k = 0; k < KK; ++k) {
                const int id = idxp[p2 * 16 + k];              // uniform -> scalar load
                const float fv = inb[(size_t)id * 64 + lane];  // coalesced gather
                const float4 q0 = *(const float4*)(hb + k * 16);
                const float4 q1 = *(const float4*)(hb + k * 16 + 4);
                a0 = fmaf(fv, q0.x, a0); a1 = fmaf(fv, q0.y, a1);
                a2 = fmaf(fv, q0.z, a2); a3 = fmaf(fv, q0.w, a3);
                a4 = fmaf(fv, q1.x, a4); a5 = fmaf(fv, q1.y, a5);
                a6 = fmaf(fv, q1.z, a6); a7 = fmaf(fv, q1.w, a7);
            }
            // k''(half) = cin*8 + ml  -> 16B at byte cin*16 in row p2, XOR-swizzled
            char* fbb = (char*)s_fb;
            const unsigned int off =
                ((unsigned)(p2 * 1024 + lane * 16)) ^ ((unsigned)(p2 & 7) << 4);
            *(uint4*)(fbb + off) = make_uint4(pack_bf2(a0, a1), pack_bf2(a2, a3),
                                              pack_bf2(a4, a5), pack_bf2(a6, a7));
        }
        __threadfence_block();

        // ---- phase 3: 16 k-steps x 4 cout-tiles on this half ----
        const char* fbb = (const char*)s_fb;
        const unsigned int ab = (unsigned)(arow & 7) * 1024u + (unsigned)hi * 16u;
        const unsigned int xr = (unsigned)(arow & 7) << 4;
        #pragma unroll
        for (int kk = 0; kk < 16; ++kk) {
            const bf16x8 av = *(const bf16x8*)(fbb + ((ab + (unsigned)kk * 64u) ^ xr));
            const int wo = h * 512 + kk * 32;
            acc0 = __builtin_amdgcn_mfma_f32_16x16x32_bf16(av, *(const bf16x8*)(wb0 + wo), acc0, 0, 0, 0);
            acc1 = __builtin_amdgcn_mfma_f32_16x16x32_bf16(av, *(const bf16x8*)(wb1 + wo), acc1, 0, 0, 0);
            acc2 = __builtin_amdgcn_mfma_f32_16x16x32_bf16(av, *(const bf16x8*)(wb2 + wo), acc2, 0, 0, 0);
            acc3 = __builtin_amdgcn_mfma_f32_16x16x32_bf16(av, *(const bf16x8*)(wb3 + wo), acc3, 0, 0, 0);
        }
        __threadfence_block();                   // reads retired before next-half writes
    }

    // rows 8-15 are duplicates of 0-7; store only rows 0-7 (hi = 0,1)
    if (hi < 2) {
        const float bv0 = bias[ 0 + arow];
        const float bv1 = bias[16 + arow];
        const float bv2 = bias[32 + arow];
        const float bv3 = bias[48 + arow];
        #pragma unroll
        for (int r = 0; r < 4; ++r) {
            float* orow = out + ((size_t)(pt0 + hi * 4 + r)) * 64;
            orow[ 0 + arow] = acc0[r] + bv0;
            orow[16 + arow] = acc1[r] + bv1;
            orow[32 + arow] = acc2[r] + bv2;
            orow[48 + arow] = acc3[r] + bv3;
        }
    }
}

// ================= fallback: proven round-6 monolith =================
__global__ __launch_bounds__(256, 2) void ptconv_fused(
    const float* __restrict__ inp, const float* __restrict__ points,
    const float* __restrict__ next_pts, const int* __restrict__ indices,
    const unsigned short* __restrict__ Wt, const float* __restrict__ A1f,
    const float* __restrict__ bias,
    const float* __restrict__ l2w, const float* __restrict__ l2b,
    const float* __restrict__ l3w, const float* __restrict__ l3b,
    float* __restrict__ out)
{
    const int t    = threadIdx.x;
    const int lane = t & 63;
    const int w    = t >> 6;
    const int pt0  = blockIdx.x * P;
    const int b    = pt0 >> 13;

    __shared__ float s_A1[32][4];
    __shared__ float s_w2[32][16];
    __shared__ float s_w3[16][16];
    __shared__ float s_b2[16], s_b3[16];
    __shared__ int   s_idx[P][KK];
    __shared__ float s_nxt[P][3];
    __shared__ float s_h3[P][264];
    __shared__ unsigned short s_fb[P][512];

    if (t < 128) ((float*)s_A1)[t] = A1f[t];
    for (int i = t; i < 512; i += 256) ((float*)s_w2)[i] = l2w[i];
    if (t < 256) ((float*)s_w3)[t] = l3w[t];
    if (t < 16)  { s_b2[t] = l2b[t]; s_b3[t] = l3b[t]; }
    ((int*)s_idx)[t] = indices[(size_t)pt0 * KK + t];
    if (t < P * 3) ((float*)s_nxt)[t] = next_pts[(size_t)pt0 * 3 + t];
    __syncthreads();

    {
        const int p = t >> 4, k = t & 15;
        const int id = s_idx[p][k];
        const float* pp = points + ((size_t)(b * NN + id)) * 3;
        const float px = pp[0] - s_nxt[p][0];
        const float py = pp[1] - s_nxt[p][1];
        const float pz = pp[2] - s_nxt[p][2];
        float h1[32];
        #pragma unroll
        for (int j = 0; j < 32; ++j) {
            const float4 a = *(const float4*)&s_A1[j][0];
            h1[j] = fmaxf(fmaf(px, a.x, fmaf(py, a.y, fmaf(pz, a.z, a.w))), 0.f);
        }
        float h2[16];
        #pragma unroll
        for (int j = 0; j < 16; ++j) h2[j] = s_b2[j];
        #pragma unroll
        for (int i = 0; i < 32; ++i) {
            const float4 q0 = *(const float4*)&s_w2[i][0];
            const float4 q1 = *(const float4*)&s_w2[i][4];
            const float4 q2 = *(const float4*)&s_w2[i][8];
            const float4 q3 = *(const float4*)&s_w2[i][12];
            h2[0]  = fmaf(h1[i], q0.x, h2[0]);  h2[1]  = fmaf(h1[i], q0.y, h2[1]);
            h2[2]  = fmaf(h1[i], q0.z, h2[2]);  h2[3]  = fmaf(h1[i], q0.w, h2[3]);
            h2[4]  = fmaf(h1[i], q1.x, h2[4]);  h2[5]  = fmaf(h1[i], q1.y, h2[5]);
            h2[6]  = fmaf(h1[i], q1.z, h2[6]);  h2[7]  = fmaf(h1[i], q1.w, h2[7]);
            h2[8]  = fmaf(h1[i], q2.x, h2[8]);  h2[9]  = fmaf(h1[i], q2.y, h2[9]);
            h2[10] = fmaf(h1[i], q2.z, h2[10]); h2[11] = fmaf(h1[i], q2.w, h2[11]);
            h2[12] = fmaf(h1[i], q3.x, h2[12]); h2[13] = fmaf(h1[i], q3.y, h2[13]);
            h2[14] = fmaf(h1[i], q3.z, h2[14]); h2[15] = fmaf(h1[i], q3.w, h2[15]);
        }
        #pragma unroll
        for (int j = 0; j < 16; ++j) h2[j] = fmaxf(h2[j], 0.f);
        float h3[16];
        #pragma unroll
        for (int j = 0; j < 16; ++j) h3[j] = s_b3[j];
        #pragma unroll
        for (int i = 0; i < 16; ++i) {
            const float4 q0 = *(const float4*)&s_w3[i][0];
            const float4 q1 = *(const float4*)&s_w3[i][4];
            const float4 q2 = *(const float4*)&s_w3[i][8];
            const float4 q3 = *(const float4*)&s_w3[i][12];
            h3[0]  = fmaf(h2[i], q0.x, h3[0]);  h3[1]  = fmaf(h2[i], q0.y, h3[1]);
            h3[2]  = fmaf(h2[i], q0.z, h3[2]);  h3[3]  = fmaf(h2[i], q0.w, h3[3]);
            h3[4]  = fmaf(h2[i], q1.x, h3[4]);  h3[5]  = fmaf(h2[i], q1.y, h3[5]);
            h3[6]  = fmaf(h2[i], q1.z, h3[6]);  h3[7]  = fmaf(h2[i], q1.w, h3[7]);
            h3[8]  = fmaf(h2[i], q2.x, h3[8]);  h3[9]  = fmaf(h2[i], q2.y, h3[9]);
            h3[10] = fmaf(h2[i], q2.z, h3[10]); h3[11] = fmaf(h2[i], q2.w, h3[11]);
            h3[12] = fmaf(h2[i], q3.x, h3[12]); h3[13] = fmaf(h2[i], q3.y, h3[13]);
            h3[14] = fmaf(h2[i], q3.z, h3[14]); h3[15] = fmaf(h2[i], q3.w, h3[15]);
        }
        #pragma unroll
        for (int m = 0; m < 16; ++m)
            s_h3[p][k * 16 + ((m + k) & 15)] = fmaxf(h3[m], 0.f);
    }
    __syncthreads();

    uint4 hold[4];
    {
        #pragma unroll
        for (int j = 0; j < 4; ++j) {
            const int p2 = w * 4 + j;
            float accf[16];
            #pragma unroll
            for (int m = 0; m < 16; ++m) accf[m] = 0.f;
            #pragma unroll
            for (int k = 0; k < 16; ++k) {
                const int id = s_idx[p2][k];
                const float fv = inp[((size_t)(b * NN + id)) * 64 + lane];
                const float* hr = &s_h3[p2][k * 16];
                float hv[16];
                #pragma unroll
                for (int q = 0; q < 4; ++q) {
                    const float4 qq = *(const float4*)(hr + q * 4);
                    hv[q * 4 + 0] = qq.x; hv[q * 4 + 1] = qq.y;
                    hv[q * 4 + 2] = qq.z; hv[q * 4 + 3] = qq.w;
                }
                #pragma unroll
                for (int m = 0; m < 16; ++m)
                    accf[m] = fmaf(fv, hv[(m + k) & 15], accf[m]);
            }
            unsigned int pk[8];
            #pragma unroll
            for (int i = 0; i < 8; ++i)
                pk[i] = pack_bf2(accf[2 * i], accf[2 * i + 1]);
            hold[j] = make_uint4(pk[4], pk[5], pk[6], pk[7]);
            char* fbb = (char*)s_fb;
            const unsigned int off =
                ((unsigned)(p2 * 1024 + lane * 16)) ^ ((unsigned)(p2 & 7) << 4);
            *(uint4*)(fbb + off) = make_uint4(pk[0], pk[1], pk[2], pk[3]);
        }
    }
    __syncthreads();

    {
        const int arow = lane & 15;
        const int hi   = lane >> 4;
        const unsigned int abase = (unsigned)arow * 1024u + (unsigned)hi * 16u;
        const unsigned int xr    = (unsigned)(arow & 7) << 4;
        const unsigned short* wb = Wt + (size_t)(w * 16 + arow) * 1024 + hi * 8;
        const char* fbb = (const char*)s_fb;
        f32x4 acc = {0.f, 0.f, 0.f, 0.f};
        #pragma unroll
        for (int kk = 0; kk < 16; ++kk) {
            const bf16x8 av = *(const bf16x8*)(fbb + ((abase + (unsigned)kk * 64u) ^ xr));
            const bf16x8 bv = *(const bf16x8*)(wb + kk * 32);
            acc = __builtin_amdgcn_mfma_f32_16x16x32_bf16(av, bv, acc, 0, 0, 0);
        }
        __syncthreads();
        #pragma unroll
        for (int j = 0; j < 4; ++j) {
            const int p2 = w * 4 + j;
            char* fbw = (char*)s_fb;
            const unsigned int off =
                ((unsigned)(p2 * 1024 + lane * 16)) ^ ((unsigned)(p2 & 7) << 4);
            *(uint4*)(fbw + off) = hold[j];
        }
        __syncthreads();
        #pragma unroll
        for (int kk = 0; kk < 16; ++kk) {
            const bf16x8 av = *(const bf16x8*)(fbb + ((abase + (unsigned)kk * 64u) ^ xr));
            const bf16x8 bv = *(const bf16x8*)(wb + 512 + kk * 32);
            acc = __builtin_amdgcn_mfma_f32_16x16x32_bf16(av, bv, acc, 0, 0, 0);
        }
        const float bvs = bias[w * 16 + arow];
        #pragma unroll
        for (int r = 0; r < 4; ++r)
            out[((size_t)(pt0 + hi * 4 + r)) * 64 + w * 16 + arow] = acc[r] + bvs;
    }
}

extern "C" void kernel_launch(void* const* d_in, const int* in_sizes, int n_in,
                              void* d_out, int out_size, void* d_ws, size_t ws_size,
                              hipStream_t stream) {
    const float* inp      = (const float*)d_in[0];
    const float* points   = (const float*)d_in[1];
    const float* next_pts = (const float*)d_in[2];
    const int*   indices  = (const int*)  d_in[3];
    const float* weight   = (const float*)d_in[4];
    const float* bias     = (const float*)d_in[5];
    const float* centers  = (const float*)d_in[6];
    const float* l1w      = (const float*)d_in[7];
    const float* l1b      = (const float*)d_in[8];
    const float* l2w      = (const float*)d_in[9];
    const float* l2b      = (const float*)d_in[10];
    const float* l3w      = (const float*)d_in[11];
    const float* l3b      = (const float*)d_in[12];
    float* outp = (float*)d_out;

    unsigned short* Wt  = (unsigned short*)d_ws;            // 128 KB
    float*          A1f = (float*)((char*)d_ws + 131072);   // 512 B
    const size_t H3_OFF = (size_t)1 << 20;                  // 1 MB
    const size_t need   = H3_OFF + (size_t)BB * NN * KK * 16 * 4;  // 1 MB + 32 MB

    prep_w<<<256, 256, 0, stream>>>(weight, Wt);
    prep_fold<<<1, 32, 0, stream>>>(l1w, l1b, centers, A1f);

    if (ws_size >= need) {
        float* h3g = (float*)((char*)d_ws + H3_OFF);
        mlp_kernel<<<2048, 256, 0, stream>>>(points, next_pts, indices, A1f,
                                             l2w, l2b, l3w, l3b, h3g);
        gemm_kernel<<<BB * NN / PW, 64, 0, stream>>>(inp, indices, h3g, Wt, bias, outp);
    } else {
        ptconv_fused<<<2048, 256, 0, stream>>>(inp, points, next_pts, indices,
                                               Wt, A1f, bias,
                                               l2w, l2b, l3w, l3b, outp);
    }
}

// Round 9
// 85.648 us; speedup vs baseline: 2.6031x; 2.6031x over previous
//
#include <hip/hip_runtime.h>

#define BB    4
#define NN    8192
#define KK    16
#define CIN   64
#define COUTC 64
#define P     16           // points per block (= MFMA M-tile)

typedef short bf16x8 __attribute__((ext_vector_type(8)));
typedef float f32x4  __attribute__((ext_vector_type(4)));
typedef float f32x2  __attribute__((ext_vector_type(2)));

__device__ __forceinline__ unsigned short f2bf_rne(float f) {
    unsigned int u = __builtin_bit_cast(unsigned int, f);
    u += 0x7fffu + ((u >> 16) & 1u);
    return (unsigned short)(u >> 16);
}

// Wt[cout][k'], k' = m*64 + cin, scale 1/16 folded in.  (round-2 verbatim)
__global__ __launch_bounds__(256) void prep_w(const float* __restrict__ W,
                                              unsigned short* __restrict__ Wt) {
    const int o    = blockIdx.x * 256 + threadIdx.x;   // 65536 total
    const int cout = o >> 10;
    const int kp   = o & 1023;
    const int m    = kp >> 6;
    const int cin  = kp & 63;
    Wt[o] = f2bf_rne(W[(cin * 16 + m) * 64 + cout] * (1.0f / 16.0f));
}

// folded layer-1, SoA: A1[c][j], c = {a0,a1,a2,b'}
__global__ void prep_fold(const float* __restrict__ l1w, const float* __restrict__ l1b,
                          const float* __restrict__ centers, float* __restrict__ A1) {
    const int t = threadIdx.x;     // 32 threads
    float bb = l1b[t];
    float a0 = 0.f, a1 = 0.f, a2 = 0.f;
    for (int c = 0; c < 16; ++c) {
        const float w0 = l1w[(c     ) * 32 + t];
        const float w1 = l1w[(16 + c) * 32 + t];
        const float w2 = l1w[(32 + c) * 32 + t];
        a0 += w0; a1 += w1; a2 += w2;
        bb -= centers[c] * w0 + centers[16 + c] * w1 + centers[32 + c] * w2;
    }
    A1[0 * 32 + t] = a0; A1[1 * 32 + t] = a1; A1[2 * 32 + t] = a2; A1[3 * 32 + t] = bb;
}

__global__ __launch_bounds__(256, 2) void ptconv_fused(
    const float* __restrict__ inp,       // [B,N,CIN]
    const float* __restrict__ points,    // [B,N,3]
    const float* __restrict__ next_pts,  // [B,N,3]
    const int*   __restrict__ indices,   // [B,N,K]
    const unsigned short* __restrict__ Wt, // [COUT][1024] bf16 (prep)
    const float* __restrict__ A1f,       // [4][32] folded layer-1 (prep, SoA)
    const float* __restrict__ bias,      // [COUT]
    const float* __restrict__ l2w, const float* __restrict__ l2b,  // [32,16],[16]
    const float* __restrict__ l3w, const float* __restrict__ l3b,  // [16,16],[16]
    float* __restrict__ out)             // [B,N,COUT]
{
    const int t    = threadIdx.x;
    const int lane = t & 63;
    const int w    = t >> 6;             // wave id 0..3
    const int pt0  = blockIdx.x * P;
    const int b    = pt0 >> 13;          // pt0 / NN

    __shared__ float s_A1[4][32];        // 512 B (SoA)
    __shared__ float s_w2[32][16];       // 2 KB
    __shared__ float s_w3[16][16];       // 1 KB
    __shared__ float s_b2[16], s_b3[16];
    __shared__ int   s_idx[P][KK];       // 1 KB
    __shared__ float s_nxt[P][3];
    __shared__ float s_h3[P][264];       // 16.9 KB, pos (m+2k)&15 holds h3[m]
    __shared__ unsigned short s_fb[P][1024]; // 32 KB bf16, k' = m*64+cin, XOR-swizzled
    // total ~54.8 KB -> 2 blocks/CU (round-2 proven)

    // ---------------- setup ----------------
    if (t < 128) ((float*)s_A1)[t] = A1f[t];
    for (int i = t; i < 512; i += 256) ((float*)s_w2)[i] = l2w[i];
    if (t < 256) ((float*)s_w3)[t] = l3w[t];
    if (t < 16)  { s_b2[t] = l2b[t]; s_b3[t] = l3b[t]; }
    ((int*)s_idx)[t] = indices[(size_t)pt0 * KK + t];     // 256 = P*KK
    if (t < P * 3) ((float*)s_nxt)[t] = next_pts[(size_t)pt0 * 3 + t];
    __syncthreads();

    const f32x2 zero2 = {0.f, 0.f};

    // ---------------- phase 1: MLP in packed f32, thread = (p,k) ----------------
    {
        const int p = t >> 4, k = t & 15;
        const int id = s_idx[p][k];
        const float* pp = points + ((size_t)(b * NN + id)) * 3;
        const float px = pp[0] - s_nxt[p][0];
        const float py = pp[1] - s_nxt[p][1];
        const float pz = pp[2] - s_nxt[p][2];
        const f32x2 px2 = {px, px}, py2 = {py, py}, pz2 = {pz, pz};

        const f32x2* A0 = (const f32x2*)&s_A1[0][0];
        const f32x2* A1v = (const f32x2*)&s_A1[1][0];
        const f32x2* A2 = (const f32x2*)&s_A1[2][0];
        const f32x2* A3 = (const f32x2*)&s_A1[3][0];
        f32x2 h1[16];
        #pragma unroll
        for (int j = 0; j < 16; ++j) {
            f32x2 a = __builtin_elementwise_fma(pz2, A2[j], A3[j]);
            a = __builtin_elementwise_fma(py2, A1v[j], a);
            a = __builtin_elementwise_fma(px2, A0[j], a);
            h1[j] = __builtin_elementwise_max(a, zero2);
        }

        f32x2 h2[8];
        {
            const f32x2* b2 = (const f32x2*)&s_b2[0];
            #pragma unroll
            for (int j = 0; j < 8; ++j) h2[j] = b2[j];
        }
        #pragma unroll
        for (int i = 0; i < 32; ++i) {
            const float hv = h1[i >> 1][i & 1];
            const f32x2 hvv = {hv, hv};
            const f32x2* wr = (const f32x2*)&s_w2[i][0];
            #pragma unroll
            for (int j = 0; j < 8; ++j)
                h2[j] = __builtin_elementwise_fma(hvv, wr[j], h2[j]);
        }
        #pragma unroll
        for (int j = 0; j < 8; ++j) h2[j] = __builtin_elementwise_max(h2[j], zero2);

        f32x2 h3[8];
        {
            const f32x2* b3 = (const f32x2*)&s_b3[0];
            #pragma unroll
            for (int j = 0; j < 8; ++j) h3[j] = b3[j];
        }
        #pragma unroll
        for (int i = 0; i < 16; ++i) {
            const float hv = h2[i >> 1][i & 1];
            const f32x2 hvv = {hv, hv};
            const f32x2* wr = (const f32x2*)&s_w3[i][0];
            #pragma unroll
            for (int j = 0; j < 8; ++j)
                h3[j] = __builtin_elementwise_fma(hvv, wr[j], h3[j]);
        }
        // pair-preserving rotated store: pos (2j+2k)&15 holds {h3[2j], h3[2j+1]}
        #pragma unroll
        for (int j = 0; j < 8; ++j) {
            const f32x2 v = __builtin_elementwise_max(h3[j], zero2);
            const int pos = (2 * j + 2 * k) & 15;
            *(f32x2*)&s_h3[p][k * 16 + pos] = v;
        }
    }
    __syncthreads();

    // ---------------- phase 2: f[p][cin][m] in packed f32, lane = cin ----------------
    {
        #pragma unroll
        for (int j = 0; j < 4; ++j) {
            const int p2 = w * 4 + j;
            f32x2 acc2[8];
            #pragma unroll
            for (int i = 0; i < 8; ++i) acc2[i] = zero2;
            #pragma unroll
            for (int k = 0; k < 16; ++k) {
                const int id = s_idx[p2][k];
                const float fv = inp[((size_t)(b * NN + id)) * 64 + lane];
                const f32x4* hr = (const f32x4*)&s_h3[p2][k * 16];
                const f32x4 q0 = hr[0], q1 = hr[1], q2 = hr[2], q3 = hr[3];
                f32x2 hv2[8];
                hv2[0] = __builtin_shufflevector(q0, q0, 0, 1);
                hv2[1] = __builtin_shufflevector(q0, q0, 2, 3);
                hv2[2] = __builtin_shufflevector(q1, q1, 0, 1);
                hv2[3] = __builtin_shufflevector(q1, q1, 2, 3);
                hv2[4] = __builtin_shufflevector(q2, q2, 0, 1);
                hv2[5] = __builtin_shufflevector(q2, q2, 2, 3);
                hv2[6] = __builtin_shufflevector(q3, q3, 0, 1);
                hv2[7] = __builtin_shufflevector(q3, q3, 2, 3);
                const f32x2 fv2 = {fv, fv};
                #pragma unroll
                for (int i = 0; i < 8; ++i)
                    acc2[i] = __builtin_elementwise_fma(fv2, hv2[(i + k) & 7], acc2[i]);
            }
            // 16 conflict-free b16 writes, k' = m*64 + cin (round-2 pattern)
            const unsigned int rowbase = (unsigned)p2 * 2048u;
            const unsigned int xr = (unsigned)(p2 & 7) << 4;
            char* fbb = (char*)s_fb;
            #pragma unroll
            for (int i = 0; i < 8; ++i) {
                const unsigned int off0 = (rowbase + (unsigned)((2 * i)     * 64 + lane) * 2u) ^ xr;
                const unsigned int off1 = (rowbase + (unsigned)((2 * i + 1) * 64 + lane) * 2u) ^ xr;
                *(unsigned short*)(fbb + off0) = f2bf_rne(acc2[i][0]);
                *(unsigned short*)(fbb + off1) = f2bf_rne(acc2[i][1]);
            }
        }
    }
    __syncthreads();

    // ---------------- phase 3: MFMA, wave w -> couts [w*16, w*16+16)  (round-2 verbatim) ----------------
    {
        const int arow = lane & 15;      // A row = point ; B col = cout_local
        const int hi   = lane >> 4;
        const unsigned int abase = (unsigned)arow * 2048u + (unsigned)hi * 16u;
        const unsigned int xr    = (unsigned)(arow & 7) << 4;
        const unsigned short* wb = Wt + (size_t)(w * 16 + arow) * 1024 + hi * 8;
        const char* fbb = (const char*)s_fb;
        f32x4 acc = {0.f, 0.f, 0.f, 0.f};
        #pragma unroll
        for (int kk = 0; kk < 32; ++kk) {
            const bf16x8 av = *(const bf16x8*)(fbb + ((abase + (unsigned)kk * 64u) ^ xr));
            const bf16x8 bv = *(const bf16x8*)(wb + kk * 32);
            acc = __builtin_amdgcn_mfma_f32_16x16x32_bf16(av, bv, acc, 0, 0, 0);
        }
        const float bvs = bias[w * 16 + arow];
        #pragma unroll
        for (int r = 0; r < 4; ++r) {
            const int prow = hi * 4 + r;
            out[((size_t)(pt0 + prow)) * 64 + w * 16 + arow] = acc[r] + bvs;
        }
    }
}

extern "C" void kernel_launch(void* const* d_in, const int* in_sizes, int n_in,
                              void* d_out, int out_size, void* d_ws, size_t ws_size,
                              hipStream_t stream) {
    const float* inp      = (const float*)d_in[0];
    const float* points   = (const float*)d_in[1];
    const float* next_pts = (const float*)d_in[2];
    const int*   indices  = (const int*)  d_in[3];
    const float* weight   = (const float*)d_in[4];
    const float* bias     = (const float*)d_in[5];
    const float* centers  = (const float*)d_in[6];
    const float* l1w      = (const float*)d_in[7];
    const float* l1b      = (const float*)d_in[8];
    const float* l2w      = (const float*)d_in[9];
    const float* l2b      = (const float*)d_in[10];
    const float* l3w      = (const float*)d_in[11];
    const float* l3b      = (const float*)d_in[12];
    float* outp = (float*)d_out;

    unsigned short* Wt  = (unsigned short*)d_ws;            // 128 KB
    float*          A1f = (float*)((char*)d_ws + 131072);   // 512 B

    prep_w<<<256, 256, 0, stream>>>(weight, Wt);
    prep_fold<<<1, 32, 0, stream>>>(l1w, l1b, centers, A1f);

    const int grid = (BB * NN) / P;               // 2048 blocks
    ptconv_fused<<<grid, 256, 0, stream>>>(inp, points, next_pts, indices,
                                           Wt, A1f, bias,
                                           l2w, l2b, l3w, l3b, outp);
}

// Round 10
// 66.010 us; speedup vs baseline: 3.3775x; 1.2975x over previous
//
#include <hip/hip_runtime.h>

#define BB    4
#define NN    8192
#define KK    16
#define CIN   64
#define COUTC 64
#define P     16           // points per block (= MFMA M-tile)

typedef short bf16x8 __attribute__((ext_vector_type(8)));
typedef float f32x4  __attribute__((ext_vector_type(4)));
typedef float f32x2  __attribute__((ext_vector_type(2)));

__device__ __forceinline__ unsigned short f2bf_rne(float f) {
    unsigned int u = __builtin_bit_cast(unsigned int, f);
    u += 0x7fffu + ((u >> 16) & 1u);
    return (unsigned short)(u >> 16);
}

__device__ __forceinline__ unsigned int pack_bf2(float lo, float hi) {
    return (unsigned int)f2bf_rne(lo) | ((unsigned int)f2bf_rne(hi) << 16);
}

// Wt[cout][k'], k' = m*64 + cin, scale 1/16 folded in.  (round-2 verbatim)
__global__ __launch_bounds__(256) void prep_w(const float* __restrict__ W,
                                              unsigned short* __restrict__ Wt) {
    const int o    = blockIdx.x * 256 + threadIdx.x;   // 65536 total
    const int cout = o >> 10;
    const int kp   = o & 1023;
    const int m    = kp >> 6;
    const int cin  = kp & 63;
    Wt[o] = f2bf_rne(W[(cin * 16 + m) * 64 + cout] * (1.0f / 16.0f));
}

// folded layer-1, SoA: A1[c][j], c = {a0,a1,a2,b'}
__global__ void prep_fold(const float* __restrict__ l1w, const float* __restrict__ l1b,
                          const float* __restrict__ centers, float* __restrict__ A1) {
    const int t = threadIdx.x;     // 32 threads
    float bb = l1b[t];
    float a0 = 0.f, a1 = 0.f, a2 = 0.f;
    for (int c = 0; c < 16; ++c) {
        const float w0 = l1w[(c     ) * 32 + t];
        const float w1 = l1w[(16 + c) * 32 + t];
        const float w2 = l1w[(32 + c) * 32 + t];
        a0 += w0; a1 += w1; a2 += w2;
        bb -= centers[c] * w0 + centers[16 + c] * w1 + centers[32 + c] * w2;
    }
    A1[0 * 32 + t] = a0; A1[1 * 32 + t] = a1; A1[2 * 32 + t] = a2; A1[3 * 32 + t] = bb;
}

// inp f32 -> bf16 copy (gathers then load 2B, no per-use cvt)
__global__ __launch_bounds__(256) void prep_inp(const float* __restrict__ inp,
                                                unsigned short* __restrict__ inp_bf) {
    const int i = blockIdx.x * 256 + threadIdx.x;      // 2M total
    inp_bf[i] = f2bf_rne(inp[i]);
}

__global__ __launch_bounds__(256, 2) void ptconv_fused(
    const float* __restrict__ inp,       // [B,N,CIN] (phase-1 unused; kept for fallback symmetry)
    const unsigned short* __restrict__ inp_bf, // [B,N,CIN] bf16 (prep)
    const float* __restrict__ points,    // [B,N,3]
    const float* __restrict__ next_pts,  // [B,N,3]
    const int*   __restrict__ indices,   // [B,N,K]
    const unsigned short* __restrict__ Wt, // [COUT][1024] bf16 (prep)
    const float* __restrict__ A1f,       // [4][32] folded layer-1 (prep, SoA)
    const float* __restrict__ bias,      // [COUT]
    const float* __restrict__ l2w, const float* __restrict__ l2b,  // [32,16],[16]
    const float* __restrict__ l3w, const float* __restrict__ l3b,  // [16,16],[16]
    float* __restrict__ out)             // [B,N,COUT]
{
    const int t    = threadIdx.x;
    const int lane = t & 63;
    const int w    = t >> 6;             // wave id 0..3
    const int pt0  = blockIdx.x * P;
    const int b    = pt0 >> 13;          // pt0 / NN

    // s_h3t[p][m][k] bf16 (h3 transposed) ; s_fb = f bf16, k' = m*64+cin, XOR-swizzled
    __shared__ unsigned short s_h3t[P][16][16];   // 8 KB
    __shared__ unsigned short s_fb[P][1024];      // 32 KB
    // total 40 KB -> up to 4 blocks/CU

    const f32x2 zero2 = {0.f, 0.f};

    // ---------------- phase 1: MLP packed f32, weights via scalar loads ----------------
    {
        const int p = t >> 4, k = t & 15;
        const int pt = pt0 + p;
        const int id = indices[(size_t)pt0 * KK + t];  // coalesced
        const float* pp = points + ((size_t)(b * NN + id)) * 3;
        const float* np = next_pts + (size_t)pt * 3;
        const float px = pp[0] - np[0];
        const float py = pp[1] - np[1];
        const float pz = pp[2] - np[2];
        const f32x2 px2 = {px, px}, py2 = {py, py}, pz2 = {pz, pz};

        const f32x2* A0  = (const f32x2*)(A1f);
        const f32x2* A1v = (const f32x2*)(A1f + 32);
        const f32x2* A2  = (const f32x2*)(A1f + 64);
        const f32x2* A3  = (const f32x2*)(A1f + 96);
        f32x2 h1[16];
        #pragma unroll
        for (int j = 0; j < 16; ++j) {
            f32x2 a = __builtin_elementwise_fma(pz2, A2[j], A3[j]);
            a = __builtin_elementwise_fma(py2, A1v[j], a);
            a = __builtin_elementwise_fma(px2, A0[j], a);
            h1[j] = __builtin_elementwise_max(a, zero2);
        }

        f32x2 h2[8];
        {
            const f32x2* b2p = (const f32x2*)l2b;
            #pragma unroll
            for (int j = 0; j < 8; ++j) h2[j] = b2p[j];
        }
        #pragma unroll
        for (int i = 0; i < 32; ++i) {
            const float hv = h1[i >> 1][i & 1];
            const f32x2 hvv = {hv, hv};
            const f32x2* wr = (const f32x2*)(l2w + i * 16);   // uniform -> s_load
            #pragma unroll
            for (int j = 0; j < 8; ++j)
                h2[j] = __builtin_elementwise_fma(hvv, wr[j], h2[j]);
        }
        #pragma unroll
        for (int j = 0; j < 8; ++j) h2[j] = __builtin_elementwise_max(h2[j], zero2);

        f32x2 h3v[8];
        {
            const f32x2* b3p = (const f32x2*)l3b;
            #pragma unroll
            for (int j = 0; j < 8; ++j) h3v[j] = b3p[j];
        }
        #pragma unroll
        for (int i = 0; i < 16; ++i) {
            const float hv = h2[i >> 1][i & 1];
            const f32x2 hvv = {hv, hv};
            const f32x2* wr = (const f32x2*)(l3w + i * 16);   // uniform -> s_load
            #pragma unroll
            for (int j = 0; j < 8; ++j)
                h3v[j] = __builtin_elementwise_fma(hvv, wr[j], h3v[j]);
        }
        // transposed bf16 store: s_h3t[p][m][k]
        #pragma unroll
        for (int j = 0; j < 8; ++j) {
            const f32x2 v = __builtin_elementwise_max(h3v[j], zero2);
            s_h3t[p][2 * j    ][k] = f2bf_rne(v[0]);
            s_h3t[p][2 * j + 1][k] = f2bf_rne(v[1]);
        }
    }
    __syncthreads();

    // ---------------- phase 2: f = feats @ h3 via MFMA, 2 point-pairs per wave ----------------
    {
        const int arow = lane & 15;          // A-row = cin_local ; B-col = m
        const int hi   = lane >> 4;
        const int kg   = (hi & 1) * 8;       // k-group base within the 16 real k
        const unsigned short* ibase = inp_bf + (size_t)b * NN * 64;
        const int* idxg = indices + (size_t)pt0 * KK;
        const bf16x8 vzero = {0, 0, 0, 0, 0, 0, 0, 0};
        char* fbb = (char*)s_fb;

        #pragma unroll
        for (int pr = 0; pr < 2; ++pr) {
            const int pA  = w * 4 + pr * 2;
            const int pB  = pA + 1;
            const int myp = (hi < 2) ? pA : pB;

            int ids[8];
            #pragma unroll
            for (int jj = 0; jj < 8; ++jj) ids[jj] = idxg[myp * 16 + kg + jj];
            const unsigned short* rb[8];
            #pragma unroll
            for (int jj = 0; jj < 8; ++jj) rb[jj] = ibase + (size_t)ids[jj] * 64 + arow;

            // B fragments: hi<2 lanes carry pA's h3 rows (k 0..15), hi>=2 carry pB's (k 16..31)
            const bf16x8 vfull = *(const bf16x8*)&s_h3t[myp][arow][kg];
            const bf16x8 bfA = (hi < 2) ? vfull : vzero;
            const bf16x8 bfB = (hi < 2) ? vzero : vfull;

            #pragma unroll
            for (int tile = 0; tile < 4; ++tile) {
                bf16x8 af;
                #pragma unroll
                for (int jj = 0; jj < 8; ++jj) af[jj] = (short)rb[jj][tile * 16];
                const f32x4 z4 = {0.f, 0.f, 0.f, 0.f};
                const f32x4 dA = __builtin_amdgcn_mfma_f32_16x16x32_bf16(af, bfA, z4, 0, 0, 0);
                const f32x4 dB = __builtin_amdgcn_mfma_f32_16x16x32_bf16(af, bfB, z4, 0, 0, 0);
                // D[row=4*hi+r][col=arow] = F[cin=tile*16+4*hi+r][m=arow]; k' = m*64+cin
                const unsigned int base = (unsigned)(arow * 128 + tile * 32 + hi * 8);
                const unsigned int offA = ((unsigned)(pA * 2048) + base)
                                          ^ (((unsigned)((pA & 7) ^ (arow & 7))) << 4);
                const unsigned int offB = ((unsigned)(pB * 2048) + base)
                                          ^ (((unsigned)((pB & 7) ^ (arow & 7))) << 4);
                *(uint2*)(fbb + offA) = make_uint2(pack_bf2(dA[0], dA[1]), pack_bf2(dA[2], dA[3]));
                *(uint2*)(fbb + offB) = make_uint2(pack_bf2(dB[0], dB[1]), pack_bf2(dB[2], dB[3]));
            }
        }
    }
    __syncthreads();

    // ---------------- phase 3: out = f @ Wt^T, wave w -> couts [w*16, w*16+16) ----------------
    {
        const int arow = lane & 15;      // A row = point ; B col = cout_local
        const int hi   = lane >> 4;
        const unsigned int abase = (unsigned)arow * 2048u + (unsigned)hi * 16u;
        const unsigned short* wb = Wt + (size_t)(w * 16 + arow) * 1024 + hi * 8;
        const char* fbb = (const char*)s_fb;
        f32x4 acc = {0.f, 0.f, 0.f, 0.f};
        #pragma unroll
        for (int kk = 0; kk < 32; ++kk) {
            const unsigned int xr =
                ((unsigned)((arow & 7) ^ ((kk >> 1) & 7))) << 4;   // m = kk>>1 (const per step)
            const bf16x8 av = *(const bf16x8*)(fbb + ((abase + (unsigned)kk * 64u) ^ xr));
            const bf16x8 bv = *(const bf16x8*)(wb + kk * 32);
            acc = __builtin_amdgcn_mfma_f32_16x16x32_bf16(av, bv, acc, 0, 0, 0);
        }
        const float bvs = bias[w * 16 + arow];
        #pragma unroll
        for (int r = 0; r < 4; ++r) {
            const int prow = hi * 4 + r;
            out[((size_t)(pt0 + prow)) * 64 + w * 16 + arow] = acc[r] + bvs;
        }
    }
}

extern "C" void kernel_launch(void* const* d_in, const int* in_sizes, int n_in,
                              void* d_out, int out_size, void* d_ws, size_t ws_size,
                              hipStream_t stream) {
    const float* inp      = (const float*)d_in[0];
    const float* points   = (const float*)d_in[1];
    const float* next_pts = (const float*)d_in[2];
    const int*   indices  = (const int*)  d_in[3];
    const float* weight   = (const float*)d_in[4];
    const float* bias     = (const float*)d_in[5];
    const float* centers  = (const float*)d_in[6];
    const float* l1w      = (const float*)d_in[7];
    const float* l1b      = (const float*)d_in[8];
    const float* l2w      = (const float*)d_in[9];
    const float* l2b      = (const float*)d_in[10];
    const float* l3w      = (const float*)d_in[11];
    const float* l3b      = (const float*)d_in[12];
    float* outp = (float*)d_out;

    unsigned short* Wt    = (unsigned short*)d_ws;                  // 128 KB @ 0
    float*          A1f   = (float*)((char*)d_ws + 131072);         // 512 B
    unsigned short* inpbf = (unsigned short*)((char*)d_ws + (1 << 20)); // 4 MB @ 1 MB

    prep_w<<<256, 256, 0, stream>>>(weight, Wt);
    prep_fold<<<1, 32, 0, stream>>>(l1w, l1b, centers, A1f);
    prep_inp<<<(BB * NN * CIN) / 256, 256, 0, stream>>>(inp, inpbf);

    const int grid = (BB * NN) / P;               // 2048 blocks
    ptconv_fused<<<grid, 256, 0, stream>>>(inp, inpbf, points, next_pts, indices,
                                           Wt, A1f, bias,
                                           l2w, l2b, l3w, l3b, outp);
}